// Round 10
// baseline (4548.631 us; speedup 1.0000x reference)
//
#include <hip/hip_runtime.h>

#define T_STEPS 8192
#define BATCH   128
#define HID     128
#define NTHR    64                // ONE wave: no barrier, MFMA does layer 2

typedef _Float16 h8 __attribute__((ext_vector_type(8)));
typedef float    f4 __attribute__((ext_vector_type(4)));

// tanh(z) = 1 - 2/(1+e^{2z}) -- 5 instrs, NaN-free at both infinities.
__device__ __forceinline__ float fast_tanh(float z) {
    float e = __expf(2.0f * z);
    float r = __builtin_amdgcn_rcpf(1.0f + e);
    return fmaf(-2.0f, r, 1.0f);
}

// full 64-lane wave sum -> total in lane 63 (6 DPP adds, VALU pipe only).
__device__ __forceinline__ float wave_sum_l63(float x) {
#define DPP_ADD(ctrl) do {                                                        \
        int t_ = __builtin_amdgcn_update_dpp(0, __builtin_bit_cast(int, x),       \
                                             (ctrl), 0xf, 0xf, false);            \
        x += __builtin_bit_cast(float, t_); } while (0)
    DPP_ADD(0x111);  // row_shr:1
    DPP_ADD(0x112);  // row_shr:2
    DPP_ADD(0x114);  // row_shr:4
    DPP_ADD(0x118);  // row_shr:8   -> 16-lane row sums at row tails
    DPP_ADD(0x142);  // row_bcast:15
    DPP_ADD(0x143);  // row_bcast:31 -> lane 63 holds wave total
#undef DPP_ADD
    return x;
}

__device__ __forceinline__ float bcast_lane(float v, int l) {
    int r = __builtin_amdgcn_readlane(__builtin_bit_cast(int, v), l);
    return __builtin_bit_cast(float, r);
}

#define MFMA16(A, B, C) __builtin_amdgcn_mfma_f32_16x16x32_f16((A), (B), (C), 0, 0, 0)

// R24: single-wave MFMA scan. R23 post-mortem: per-SIMD issue ~70% busy ->
// the 128-dot2 stream (~4cyc each effective) IS the wall; VALU can't do
// 256 MAC/lane/step cheaper. Move layer 2 to the matrix pipe: 32 x
// mfma_f32_16x16x32_f16 (8 j-tiles x 4 k-tiles) ~= 155 cyc pipe occupancy.
// A = W2 frags (static, 128 VGPR; elem j of lane l = W2[32kt+8g+j][16mt+i],
// g=lane>>4, i=lane&15 -- the standard 16x16x32 layout; any consistent
// k-permutation of A and B cancels). B = h1 replicated into all 16 columns
// (elem depends only on g -> 4 broadcast ds_read_b128). D row map is the
// m89-VERIFIED row=(lane>>4)*4+reg, col=lane&15 (cols identical here).
// Extraction: lane owns j = 16*(i>>1)+4g+2*(i&1)+{0,1} via 30 static
// cndmask selects (no LDS round trip); tail = R23's verified tanh/DPP path.
__global__ __launch_bounds__(NTHR, 1) void odenet_scan(
    const float* __restrict__ x,
    const float* __restrict__ W1, const float* __restrict__ b1,
    const float* __restrict__ W2, const float* __restrict__ b2,
    const float* __restrict__ W3, const float* __restrict__ b3,
    float* __restrict__ out) {

    const int b    = blockIdx.x;        // batch element
    const int lane = threadIdx.x;       // 0..63, single wave
    const int g    = lane >> 4;         // k-subgroup / D row-block
    const int i    = lane & 15;         // replica index within row
    const int s0   = i & 1;             // r-pair select bit

    __shared__ __align__(16) _Float16 h1buf[128];   // h1[k] fp16, 256 B

    // ---- A fragments: a<mt>_<kt> elem j = W2[32*kt + 8*g + j][16*mt + i] ----
#define DECLA(MT, KT)                                                             \
    h8 a##MT##_##KT; {                                                            \
        const float* p_ = W2 + (32*(KT) + 8*g) * HID + 16*(MT) + i;               \
        a##MT##_##KT[0] = (_Float16)p_[0*HID];                                    \
        a##MT##_##KT[1] = (_Float16)p_[1*HID];                                    \
        a##MT##_##KT[2] = (_Float16)p_[2*HID];                                    \
        a##MT##_##KT[3] = (_Float16)p_[3*HID];                                    \
        a##MT##_##KT[4] = (_Float16)p_[4*HID];                                    \
        a##MT##_##KT[5] = (_Float16)p_[5*HID];                                    \
        a##MT##_##KT[6] = (_Float16)p_[6*HID];                                    \
        a##MT##_##KT[7] = (_Float16)p_[7*HID]; }                                  \
    asm volatile("" : "+v"(a##MT##_##KT));
#define DECLA_ROW(MT) DECLA(MT,0) DECLA(MT,1) DECLA(MT,2) DECLA(MT,3)
    DECLA_ROW(0) DECLA_ROW(1) DECLA_ROW(2) DECLA_ROW(3)
    DECLA_ROW(4) DECLA_ROW(5) DECLA_ROW(6) DECLA_ROW(7)
#undef DECLA_ROW
#undef DECLA

    // layer-1 weights for the two h1 units this lane computes (k=lane, lane+64)
    float w1xa = W1[lane],      w1ya = W1[HID + lane],      b1a = b1[lane];
    float w1xb = W1[lane + 64], w1yb = W1[HID + lane + 64], b1b = b1[lane + 64];
    // this lane's owned output units after extraction
    const int ja = 16 * (i >> 1) + 4 * g + 2 * s0;    // and ja+1
    float b2A = b2[ja], b2B = b2[ja + 1];
    float w3A = W3[ja], w3B = W3[ja + 1], b3v = b3[0];
    asm volatile("" : "+v"(w1xa), "+v"(w1ya), "+v"(b1a),
                      "+v"(w1xb), "+v"(w1yb), "+v"(b1b),
                      "+v"(b2A), "+v"(b2B), "+v"(w3A), "+v"(w3B), "+v"(b3v));

    float y    = 0.0f;
    float ybuf = 0.0f;
    if (lane == 0) out[b] = 0.0f;       // y_0 = 0

    // ---- x double-buffer: xbuf = current 64-step block, xnext = next ----
    float xbuf  = x[lane * BATCH + b];                 // block 0
    int   nb    = 64;                                  // next block base
    float xnext = x[min(nb + lane, T_STEPS - 1) * BATCH + b];
    float xv = bcast_lane(xbuf, 0);
    float ax = fmaf(xv, w1xa, b1a);     // x-side of layer 1 for t=0
    float bx = fmaf(xv, w1xb, b1b);

    const h8* hp = (const h8*)h1buf;    // frag n covers k = 8n..8n+7
    const f4 zf = {0.f, 0.f, 0.f, 0.f}; // loop-invariant zero accumulator

    for (int t = 0; t < T_STEPS - 1; ++t) {
        const int tm = t & 63;

        // ---- layer 1 (critical path from y: fma+tanh+cvt+2 b16 writes) ----
        float ha = fast_tanh(fmaf(y, w1ya, ax));
        float hb = fast_tanh(fmaf(y, w1yb, bx));
        h1buf[lane]      = (_Float16)ha;     // k = lane
        h1buf[64 + lane] = (_Float16)hb;     // k = lane + 64

        // ---- B frags: k = 32*kt + 8*g + j; addr depends on g only ->
        //      4 distinct addresses/wave = broadcast reads, conflict-free ----
        h8 B0 = hp[g];
        h8 B1 = hp[4 + g];
        h8 B2 = hp[8 + g];
        h8 B3 = hp[12 + g];

        // ---- layer 2: 32 MFMA, 8 independent 4-deep K-chains ----
#define MTILE(MT)                                                                 \
        f4 c##MT = MFMA16(a##MT##_0, B0, zf);                                     \
        c##MT = MFMA16(a##MT##_1, B1, c##MT);                                     \
        c##MT = MFMA16(a##MT##_2, B2, c##MT);                                     \
        c##MT = MFMA16(a##MT##_3, B3, c##MT);
        MTILE(0) MTILE(1) MTILE(2) MTILE(3)
        MTILE(4) MTILE(5) MTILE(6) MTILE(7)
#undef MTILE

        // ---- next step's x-side prep (fills MFMA pipe latency) ----
        const int tmn = (t + 1) & 63;
        if (tmn == 0) {                              // rotate x blocks
            xbuf = xnext;
            nb += 64;
            xnext = x[min(nb + lane, T_STEPS - 1) * BATCH + b];
        }
        float xvn = bcast_lane(xbuf, tmn);
        float axn = fmaf(xvn, w1xa, b1a);
        float bxn = fmaf(xvn, w1xb, b1b);

        // ---- extraction: z for units ja, ja+1 via 30 static cndmask ----
        // D elem r of lane l = z[16*mt + 4*g + r] (m89-verified row map);
        // lane picks mt = i>>1, r = 2*s0 (+1).
        float tA0 = s0 ? c0[2] : c0[0], tB0 = s0 ? c0[3] : c0[1];
        float tA1 = s0 ? c1[2] : c1[0], tB1 = s0 ? c1[3] : c1[1];
        float tA2 = s0 ? c2[2] : c2[0], tB2 = s0 ? c2[3] : c2[1];
        float tA3 = s0 ? c3[2] : c3[0], tB3 = s0 ? c3[3] : c3[1];
        float tA4 = s0 ? c4[2] : c4[0], tB4 = s0 ? c4[3] : c4[1];
        float tA5 = s0 ? c5[2] : c5[0], tB5 = s0 ? c5[3] : c5[1];
        float tA6 = s0 ? c6[2] : c6[0], tB6 = s0 ? c6[3] : c6[1];
        float tA7 = s0 ? c7[2] : c7[0], tB7 = s0 ? c7[3] : c7[1];
        const bool m0 = (i & 2) != 0, m1 = (i & 4) != 0, m2 = (i & 8) != 0;
        float uA0 = m0 ? tA1 : tA0, uA1 = m0 ? tA3 : tA2;
        float uA2 = m0 ? tA5 : tA4, uA3 = m0 ? tA7 : tA6;
        float uB0 = m0 ? tB1 : tB0, uB1 = m0 ? tB3 : tB2;
        float uB2 = m0 ? tB5 : tB4, uB3 = m0 ? tB7 : tB6;
        float vA0 = m1 ? uA1 : uA0, vA1 = m1 ? uA3 : uA2;
        float vB0 = m1 ? uB1 : uB0, vB1 = m1 ? uB3 : uB2;
        float zA = m2 ? vA1 : vA0;
        float zB = m2 ? vB1 : vB0;

        // ---- tanh, layer 3, wave reduce (all 64 lanes distinct j) ----
        float h2A = fast_tanh(zA + b2A);
        float h2B = fast_tanh(zB + b2B);
        float dyv = fmaf(w3A, h2A, w3B * h2B);
        float dyw = wave_sum_l63(dyv);
        float dy  = bcast_lane(dyw, 63);             // all lanes get total

        y += dy + b3v;                               // DT = 1.0

        ybuf = (lane == tm) ? y : ybuf;
        if (tm == 63)
            out[(t - 62 + lane) * BATCH + b] = ybuf;

        ax = axn; bx = bxn;
    }
    // tail: t=8128..8190 captured y_8129..y_8191 in lanes 0..62
    if (lane < 63)
        out[(T_STEPS - 63 + lane) * BATCH + b] = ybuf;
}

extern "C" void kernel_launch(void* const* d_in, const int* in_sizes, int n_in,
                              void* d_out, int out_size, void* d_ws, size_t ws_size,
                              hipStream_t stream) {
    const float* x  = (const float*)d_in[0];
    const float* W1 = (const float*)d_in[1];
    const float* b1 = (const float*)d_in[2];
    const float* W2 = (const float*)d_in[3];
    const float* b2 = (const float*)d_in[4];
    const float* W3 = (const float*)d_in[5];
    const float* b3 = (const float*)d_in[6];

    odenet_scan<<<dim3(BATCH), dim3(NTHR), 0, stream>>>(
        x, W1, b1, W2, b2, W3, b3, (float*)d_out);
}